// Round 13
// baseline (845.830 us; speedup 1.0000x reference)
//
#include <hip/hip_runtime.h>
#include <cmath>

#define B_  16
#define S_  512
#define DI  64
#define DS  64
#define RR  4
#define CH  8
#define CL  64
#define CLIPM 1.0e6f

typedef float f32x4 __attribute__((ext_vector_type(4)));

// ws layout (floats):
#define WS_U    524288        // u     [B*S][DI]
#define WS_BM   1048576       // bm    [B*S][DS]
#define WS_CML  1572864       // cml   [B][DS]
#define WS_SUM  1573888       // f32x4 sums [B][CH][DI][DS]  (8 MB)

__device__ __forceinline__ float clampM(float v) {
    return fminf(fmaxf(v, -CLIPM), CLIPM);
}

// opaque 0.0f the compiler cannot fold -> forces per-rep recompute
__device__ __forceinline__ float opaque_zero() {
    float z = 0.f;
    asm volatile("" : "+v"(z));
    return z;
}

__device__ __forceinline__ float dot64(const float* __restrict__ row,
                                       const float* xsv) {
    float a = 0.f;
    #pragma unroll
    for (int i = 0; i < 16; ++i) {
        const f32x4 w  = *reinterpret_cast<const f32x4*>(row + 4 * i);
        const f32x4 xv = *reinterpret_cast<const f32x4*>(xsv + 4 * i);
        a += w.x * xv.x + w.y * xv.y + w.z * xv.z + w.w * xv.w;
    }
    return a;
}

// k1 (R12 structure) with rep loop for measurement.
__global__ __launch_bounds__(64)
void ssm_k1(const float* __restrict__ x, const float* __restrict__ Wx,
            const float* __restrict__ bx, const float* __restrict__ Wdt,
            const float* __restrict__ bdt, const float* __restrict__ A_log,
            float* __restrict__ ws, int reps)
{
    __shared__ float xs[8][DI];
    __shared__ float dtr_s[8][RR];
    const int bt0  = blockIdx.x * 8;
    const int lane = threadIdx.x;

    #pragma unroll
    for (int r = 0; r < 8; ++r)
        xs[r][lane] = x[(size_t)(bt0 + r) * DI + lane];
    const float a_l = -expf(A_log[lane]);
    const float bxl = bx[lane];
    __syncthreads();

    f32x4 wxr[16];
    {
        const float* wr = Wx + lane * DI;
        #pragma unroll
        for (int i = 0; i < 16; ++i)
            wxr[i] = *reinterpret_cast<const f32x4*>(wr + 4 * i);
    }
    const f32x4 wdt4 = *reinterpret_cast<const f32x4*>(Wdt + lane * RR);
    const float bdtl = bdt[lane];

    for (int rep = 0; rep < reps; ++rep) {
        const float z = opaque_zero();

        float accB[8];
        #pragma unroll
        for (int r = 0; r < 8; ++r) {
            float a = bxl + z;
            #pragma unroll
            for (int i = 0; i < 16; ++i) {
                const f32x4 xv4 = *reinterpret_cast<const f32x4*>(&xs[r][4 * i]);
                a += wxr[i].x * xv4.x + wxr[i].y * xv4.y + wxr[i].z * xv4.z + wxr[i].w * xv4.w;
            }
            accB[r] = a;
        }

        if (lane < 32) {
            const int j = lane & 3, r = lane >> 2;
            dtr_s[r][j] = bx[DS + j] + z + dot64(Wx + (DS + j) * DI, &xs[r][0]);
        }
        __syncthreads();

        float qv = fmaf(a_l, a_l, z);
        #pragma unroll
        for (int off = 32; off > 0; off >>= 1) qv += __shfl_xor(qv, off);

        #pragma unroll
        for (int r = 0; r < 8; ++r) {
            float dtv = bdtl + dtr_s[r][0] * wdt4.x + dtr_s[r][1] * wdt4.y
                             + dtr_s[r][2] * wdt4.z + dtr_s[r][3] * wdt4.w;
            float sv = a_l * dtv;
            #pragma unroll
            for (int off = 32; off > 0; off >>= 1) sv += __shfl_xor(sv, off);

            const float E   = expm1f(sv);
            const float phi = (fabsf(sv) < 1e-3f)
                                ? fmaf(sv, fmaf(sv, 1.0f / 6.0f, 0.5f), 1.0f)
                                : (E / sv);
            const int bt = bt0 + r;
            ws[(size_t)bt * DI + lane]         = phi * dtv;
            ws[WS_U + (size_t)bt * DI + lane]  = xs[r][lane] * (E / qv) * a_l;
            ws[WS_BM + (size_t)bt * DI + lane] = accB[r];
        }

        if ((bt0 & (S_ - 1)) == S_ - 8) {
            ws[WS_CML + (bt0 >> 9) * DS + lane] =
                bx[DS + RR + lane] + z + dot64(Wx + (DS + RR + lane) * DI, &xs[7][0]);
        }
        __syncthreads();   // protect dtr_s rewrite next rep
    }
}

// kA (R12 LDS-staged) with rep loop.
__global__ __launch_bounds__(256)
void ssm_kA(float* __restrict__ ws, const float* __restrict__ A_log, int reps)
{
    __shared__ float pd_s[CL][4];
    __shared__ float ud_s[CL][4];
    __shared__ float bm_s[CL][DS];

    const int tid = threadIdx.x;
    const int dq  = blockIdx.x & 15;
    const int c   = (blockIdx.x >> 4) & 7;
    const int b   = blockIdx.x >> 7;
    const int d0  = dq * 4;

    const float* pg = ws + (size_t)(b * S_ + c * CL) * DI;
    const float* ug = ws + WS_U  + (size_t)(b * S_ + c * CL) * DI;
    const float* bg = ws + WS_BM + (size_t)(b * S_ + c * CL) * DI;

    if (tid < CL) {
        *reinterpret_cast<f32x4*>(&pd_s[tid][0]) =
            *reinterpret_cast<const f32x4*>(pg + (size_t)tid * DI + d0);
    } else if (tid < 2 * CL) {
        const int t = tid - CL;
        *reinterpret_cast<f32x4*>(&ud_s[t][0]) =
            *reinterpret_cast<const f32x4*>(ug + (size_t)t * DI + d0);
    }
    {
        const int col = (tid & 15) * 4;
        #pragma unroll
        for (int k = 0; k < 4; ++k) {
            const int t = (tid >> 4) + 16 * k;
            *reinterpret_cast<f32x4*>(&bm_s[t][col]) =
                *reinterpret_cast<const f32x4*>(bg + (size_t)t * DI + col);
        }
    }
    __syncthreads();

    const int w = tid >> 6;
    const int n = tid & 63;
    const int d = d0 + w;

    const float a_n   = -expf(A_log[n]);
    const float delta = (d == n) ? 1.0f : 0.0f;

    for (int rep = 0; rep < reps; ++rep) {
        const float z = opaque_zero();
        float al = 1.f + z, be = z, lo = -CLIPM + z, hi = CLIPM + z;
        #pragma unroll 8
        for (int j = 0; j < CL; ++j) {
            const float pv = pd_s[j][w];
            const float uv = ud_s[j][w];
            const float bv = bm_s[j][n];
            const float av = fmaf(pv, a_n, delta);
            const float wk = uv * bv;
            al = al * av;
            be = fmaf(av, be, wk);
            const float u1 = fmaf(av, lo, wk);
            const float u2 = fmaf(av, hi, wk);
            lo = clampM(fminf(u1, u2));
            hi = clampM(fmaxf(u1, u2));
        }
        f32x4* sum = reinterpret_cast<f32x4*>(ws + WS_SUM);
        f32x4 s = { al, be, lo, hi };
        sum[(((size_t)b * CH + c) * DI + d) * DS + n] = s;
    }
}

// wtest: writes the EXACT kC address pattern with dummy values, reps times.
// Launched BEFORE kC; kC overwrites everything -> correctness preserved.
__global__ __launch_bounds__(256)
void ssm_wtest(float* __restrict__ out, int reps)
{
    const int tid = threadIdx.x;
    const int dg  = blockIdx.x & 3;
    const int c   = (blockIdx.x >> 2) & 7;
    const int b   = blockIdx.x >> 5;
    const int dl  = tid >> 4;
    const int n0  = (tid & 15) << 2;
    const int d   = dg * 16 + dl;
    const int t0  = c * CL;

    for (int rep = 0; rep < reps; ++rep) {
        const float z = opaque_zero();
        f32x4 v = { 1.f + z, 2.f + z, 3.f + z, 4.f + z };
        #pragma unroll 4
        for (int j = 0; j < CL; ++j) {
            *reinterpret_cast<f32x4*>(
                out + 1024 + (((size_t)(b * S_ + t0 + j)) * DI + d) * DS + n0) = v;
        }
    }
}

// kC (R12 LDS-staged) with rep loop around replay+store.
__global__ __launch_bounds__(256)
void ssm_kC(const float* __restrict__ ws, const float* __restrict__ x,
            const float* __restrict__ A_log, const float* __restrict__ Dp,
            float* __restrict__ out, int reps)
{
    __shared__ float pd_s[CL][16];
    __shared__ float ud_s[CL][16];
    __shared__ float bm_s[CL][DS];

    const int tid = threadIdx.x;
    const int dg  = blockIdx.x & 3;
    const int c   = (blockIdx.x >> 2) & 7;
    const int b   = blockIdx.x >> 5;
    const int dl  = tid >> 4;
    const int n0  = (tid & 15) << 2;
    const int d0  = dg * 16;
    const int d   = d0 + dl;

    const float* pg = ws + (size_t)(b * S_ + c * CL) * DI;
    const float* ug = ws + WS_U  + (size_t)(b * S_ + c * CL) * DI;
    const float* bg = ws + WS_BM + (size_t)(b * S_ + c * CL) * DI;

    {
        const int t = tid >> 2, q = (tid & 3) * 4;
        *reinterpret_cast<f32x4*>(&pd_s[t][q]) =
            *reinterpret_cast<const f32x4*>(pg + (size_t)t * DI + d0 + q);
        *reinterpret_cast<f32x4*>(&ud_s[t][q]) =
            *reinterpret_cast<const f32x4*>(ug + (size_t)t * DI + d0 + q);
        const int col = (tid & 15) * 4;
        #pragma unroll
        for (int k = 0; k < 4; ++k) {
            const int tr = (tid >> 4) + 16 * k;
            *reinterpret_cast<f32x4*>(&bm_s[tr][col]) =
                *reinterpret_cast<const f32x4*>(bg + (size_t)tr * DI + col);
        }
    }

    const f32x4 alog4 = *reinterpret_cast<const f32x4*>(A_log + n0);
    const float an[4] = { -expf(alog4.x), -expf(alog4.y), -expf(alog4.z), -expf(alog4.w) };
    float dlt[4];
    #pragma unroll
    for (int k = 0; k < 4; ++k) dlt[k] = (d == n0 + k) ? 1.f : 0.f;

    float h0[4] = { 0.f, 0.f, 0.f, 0.f };
    {
        const f32x4* sum = reinterpret_cast<const f32x4*>(ws + WS_SUM);
        for (int c2 = 0; c2 < c; ++c2) {
            const size_t sb = (((size_t)b * CH + c2) * DI + d) * DS + n0;
            #pragma unroll
            for (int k = 0; k < 4; ++k) {
                const f32x4 s = sum[sb + k];
                h0[k] = fminf(fmaxf(fmaf(s.x, h0[k], s.y), s.z), s.w);
            }
        }
    }
    __syncthreads();

    float h[4];
    const int t0 = c * CL;
    for (int rep = 0; rep < reps; ++rep) {
        const float z = opaque_zero();
        #pragma unroll
        for (int k = 0; k < 4; ++k) h[k] = h0[k] + z;
        #pragma unroll 4
        for (int j = 0; j < CL; ++j) {
            const float pv = pd_s[j][dl];
            const float uv = ud_s[j][dl];
            const f32x4 bv = *reinterpret_cast<const f32x4*>(&bm_s[j][n0]);
            const float bva[4] = { bv.x, bv.y, bv.z, bv.w };
            #pragma unroll
            for (int k = 0; k < 4; ++k) {
                const float av = fmaf(pv, an[k], dlt[k]);
                h[k] = clampM(fmaf(av, h[k], uv * bva[k]));
            }
            f32x4 hv = { h[0], h[1], h[2], h[3] };
            *reinterpret_cast<f32x4*>(
                out + 1024 + (((size_t)(b * S_ + t0 + j)) * DI + d) * DS + n0) = hv;
        }
    }

    if (c == CH - 1) {
        const f32x4 cm = *reinterpret_cast<const f32x4*>(ws + WS_CML + b * DS + n0);
        float v = h[0] * cm.x + h[1] * cm.y + h[2] * cm.z + h[3] * cm.w;
        v += __shfl_xor(v, 1);
        v += __shfl_xor(v, 2);
        v += __shfl_xor(v, 4);
        v += __shfl_xor(v, 8);
        if ((tid & 15) == 0)
            out[b * DI + d] = v + Dp[d] * x[((size_t)(b * S_) + S_ - 1) * DI + d];
    }
}

extern "C" void kernel_launch(void* const* d_in, const int* in_sizes, int n_in,
                              void* d_out, int out_size, void* d_ws, size_t ws_size,
                              hipStream_t stream)
{
    const float* x     = (const float*)d_in[0];
    const float* Wx    = (const float*)d_in[1];
    const float* bx    = (const float*)d_in[2];
    const float* Wdt   = (const float*)d_in[3];
    const float* bdt   = (const float*)d_in[4];
    const float* A_log = (const float*)d_in[5];
    const float* Dp    = (const float*)d_in[6];
    float* out = (float*)d_out;
    float* ws  = (float*)d_ws;

    ssm_k1   <<<B_ * S_ / 8, 64, 0, stream>>>(x, Wx, bx, Wdt, bdt, A_log, ws, 24);
    ssm_kA   <<<B_ * CH * 16, 256, 0, stream>>>(ws, A_log, 20);
    ssm_wtest<<<B_ * CH * 4, 256, 0, stream>>>(out, 4);
    ssm_kC   <<<B_ * CH * 4, 256, 0, stream>>>(ws, x, A_log, Dp, out, 4);
}

// Round 14
// 288.194 us; speedup vs baseline: 2.9349x; 2.9349x over previous
//
#include <hip/hip_runtime.h>
#include <cmath>

#define B_  16
#define S_  512
#define DI  64
#define DS  64
#define RR  4
#define CH  8
#define CL  64
#define CLIPM 1.0e6f

typedef float f32x4 __attribute__((ext_vector_type(4)));

// ws layout (floats):
#define WS_U    524288        // u     [B*S][DI]
#define WS_BM   1048576       // bm    [B*S][DS]
#define WS_CML  1572864       // cml   [B][DS]
#define WS_SUM  1573888       // f32x4 sums [B][CH][DI][DS]  (8 MB)

__device__ __forceinline__ float clampM(float v) {
    return fminf(fmaxf(v, -CLIPM), CLIPM);
}

__device__ __forceinline__ float opaque_zero() {
    float z = 0.f;
    asm volatile("" : "+v"(z));
    return z;
}

__device__ __forceinline__ float dot64(const float* __restrict__ row,
                                       const float* xsv) {
    float a = 0.f;
    #pragma unroll
    for (int i = 0; i < 16; ++i) {
        const f32x4 w  = *reinterpret_cast<const f32x4*>(row + 4 * i);
        const f32x4 xv = *reinterpret_cast<const f32x4*>(xsv + 4 * i);
        a += w.x * xv.x + w.y * xv.y + w.z * xv.z + w.w * xv.w;
    }
    return a;
}

// k1: production (R12). 8 timesteps/block, Wx row in VGPRs.
__global__ __launch_bounds__(64)
void ssm_k1(const float* __restrict__ x, const float* __restrict__ Wx,
            const float* __restrict__ bx, const float* __restrict__ Wdt,
            const float* __restrict__ bdt, const float* __restrict__ A_log,
            float* __restrict__ ws)
{
    __shared__ float xs[8][DI];
    __shared__ float dtr_s[8][RR];
    const int bt0  = blockIdx.x * 8;
    const int lane = threadIdx.x;

    #pragma unroll
    for (int r = 0; r < 8; ++r)
        xs[r][lane] = x[(size_t)(bt0 + r) * DI + lane];
    const float a_l = -expf(A_log[lane]);
    const float bxl = bx[lane];
    __syncthreads();

    f32x4 wxr[16];
    {
        const float* wr = Wx + lane * DI;
        #pragma unroll
        for (int i = 0; i < 16; ++i)
            wxr[i] = *reinterpret_cast<const f32x4*>(wr + 4 * i);
    }

    float accB[8];
    #pragma unroll
    for (int r = 0; r < 8; ++r) {
        float a = bxl;
        #pragma unroll
        for (int i = 0; i < 16; ++i) {
            const f32x4 xv4 = *reinterpret_cast<const f32x4*>(&xs[r][4 * i]);
            a += wxr[i].x * xv4.x + wxr[i].y * xv4.y + wxr[i].z * xv4.z + wxr[i].w * xv4.w;
        }
        accB[r] = a;
    }

    if (lane < 32) {
        const int j = lane & 3, r = lane >> 2;
        dtr_s[r][j] = bx[DS + j] + dot64(Wx + (DS + j) * DI, &xs[r][0]);
    }
    __syncthreads();

    float qv = a_l * a_l;
    #pragma unroll
    for (int off = 32; off > 0; off >>= 1) qv += __shfl_xor(qv, off);

    const f32x4 wdt4 = *reinterpret_cast<const f32x4*>(Wdt + lane * RR);
    const float bdtl = bdt[lane];

    #pragma unroll
    for (int r = 0; r < 8; ++r) {
        float dtv = bdtl + dtr_s[r][0] * wdt4.x + dtr_s[r][1] * wdt4.y
                         + dtr_s[r][2] * wdt4.z + dtr_s[r][3] * wdt4.w;
        float sv = a_l * dtv;
        #pragma unroll
        for (int off = 32; off > 0; off >>= 1) sv += __shfl_xor(sv, off);

        const float E   = expm1f(sv);
        const float phi = (fabsf(sv) < 1e-3f)
                            ? fmaf(sv, fmaf(sv, 1.0f / 6.0f, 0.5f), 1.0f)
                            : (E / sv);
        const int bt = bt0 + r;
        ws[(size_t)bt * DI + lane]         = phi * dtv;
        ws[WS_U + (size_t)bt * DI + lane]  = xs[r][lane] * (E / qv) * a_l;
        ws[WS_BM + (size_t)bt * DI + lane] = accB[r];
    }

    if ((bt0 & (S_ - 1)) == S_ - 8) {
        ws[WS_CML + (bt0 >> 9) * DS + lane] =
            bx[DS + RR + lane] + dot64(Wx + (DS + RR + lane) * DI, &xs[7][0]);
    }
}

// kA: production (R12). LDS-staged chunk summaries.
__global__ __launch_bounds__(256)
void ssm_kA(float* __restrict__ ws, const float* __restrict__ A_log)
{
    __shared__ float pd_s[CL][4];
    __shared__ float ud_s[CL][4];
    __shared__ float bm_s[CL][DS];

    const int tid = threadIdx.x;
    const int dq  = blockIdx.x & 15;
    const int c   = (blockIdx.x >> 4) & 7;
    const int b   = blockIdx.x >> 7;
    const int d0  = dq * 4;

    const float* pg = ws + (size_t)(b * S_ + c * CL) * DI;
    const float* ug = ws + WS_U  + (size_t)(b * S_ + c * CL) * DI;
    const float* bg = ws + WS_BM + (size_t)(b * S_ + c * CL) * DI;

    if (tid < CL) {
        *reinterpret_cast<f32x4*>(&pd_s[tid][0]) =
            *reinterpret_cast<const f32x4*>(pg + (size_t)tid * DI + d0);
    } else if (tid < 2 * CL) {
        const int t = tid - CL;
        *reinterpret_cast<f32x4*>(&ud_s[t][0]) =
            *reinterpret_cast<const f32x4*>(ug + (size_t)t * DI + d0);
    }
    {
        const int col = (tid & 15) * 4;
        #pragma unroll
        for (int k = 0; k < 4; ++k) {
            const int t = (tid >> 4) + 16 * k;
            *reinterpret_cast<f32x4*>(&bm_s[t][col]) =
                *reinterpret_cast<const f32x4*>(bg + (size_t)t * DI + col);
        }
    }
    __syncthreads();

    const int w = tid >> 6;
    const int n = tid & 63;
    const int d = d0 + w;

    const float a_n   = -expf(A_log[n]);
    const float delta = (d == n) ? 1.0f : 0.0f;

    float al = 1.f, be = 0.f, lo = -CLIPM, hi = CLIPM;
    #pragma unroll 8
    for (int j = 0; j < CL; ++j) {
        const float pv = pd_s[j][w];
        const float uv = ud_s[j][w];
        const float bv = bm_s[j][n];
        const float av = fmaf(pv, a_n, delta);
        const float wk = uv * bv;
        al = al * av;
        be = fmaf(av, be, wk);
        const float u1 = fmaf(av, lo, wk);
        const float u2 = fmaf(av, hi, wk);
        lo = clampM(fminf(u1, u2));
        hi = clampM(fmaxf(u1, u2));
    }

    f32x4* sum = reinterpret_cast<f32x4*>(ws + WS_SUM);
    f32x4 s = { al, be, lo, hi };
    sum[(((size_t)b * CH + c) * DI + d) * DS + n] = s;
}

// wtest: THE measurement target this round. Writes kC's exact address
// pattern with dummy values, 12x -> lands in rocprof top-5 with counters.
// kC overwrites everything afterwards; correctness unaffected.
__global__ __launch_bounds__(256)
void ssm_wtest(float* __restrict__ out, int reps)
{
    const int tid = threadIdx.x;
    const int dg  = blockIdx.x & 3;
    const int c   = (blockIdx.x >> 2) & 7;
    const int b   = blockIdx.x >> 5;
    const int dl  = tid >> 4;
    const int n0  = (tid & 15) << 2;
    const int d   = dg * 16 + dl;
    const int t0  = c * CL;

    for (int rep = 0; rep < reps; ++rep) {
        const float z = opaque_zero();
        f32x4 v = { 1.f + z, 2.f + z, 3.f + z, 4.f + z };
        #pragma unroll 4
        for (int j = 0; j < CL; ++j) {
            *reinterpret_cast<f32x4*>(
                out + 1024 + (((size_t)(b * S_ + t0 + j)) * DI + d) * DS + n0) = v;
        }
    }
}

// kC: production (R12). LDS-staged compose+replay, f32x4 stores.
__global__ __launch_bounds__(256)
void ssm_kC(const float* __restrict__ ws, const float* __restrict__ x,
            const float* __restrict__ A_log, const float* __restrict__ Dp,
            float* __restrict__ out)
{
    __shared__ float pd_s[CL][16];
    __shared__ float ud_s[CL][16];
    __shared__ float bm_s[CL][DS];

    const int tid = threadIdx.x;
    const int dg  = blockIdx.x & 3;
    const int c   = (blockIdx.x >> 2) & 7;
    const int b   = blockIdx.x >> 5;
    const int dl  = tid >> 4;
    const int n0  = (tid & 15) << 2;
    const int d0  = dg * 16;
    const int d   = d0 + dl;

    const float* pg = ws + (size_t)(b * S_ + c * CL) * DI;
    const float* ug = ws + WS_U  + (size_t)(b * S_ + c * CL) * DI;
    const float* bg = ws + WS_BM + (size_t)(b * S_ + c * CL) * DI;

    {
        const int t = tid >> 2, q = (tid & 3) * 4;
        *reinterpret_cast<f32x4*>(&pd_s[t][q]) =
            *reinterpret_cast<const f32x4*>(pg + (size_t)t * DI + d0 + q);
        *reinterpret_cast<f32x4*>(&ud_s[t][q]) =
            *reinterpret_cast<const f32x4*>(ug + (size_t)t * DI + d0 + q);
        const int col = (tid & 15) * 4;
        #pragma unroll
        for (int k = 0; k < 4; ++k) {
            const int tr = (tid >> 4) + 16 * k;
            *reinterpret_cast<f32x4*>(&bm_s[tr][col]) =
                *reinterpret_cast<const f32x4*>(bg + (size_t)tr * DI + col);
        }
    }

    const f32x4 alog4 = *reinterpret_cast<const f32x4*>(A_log + n0);
    const float an[4] = { -expf(alog4.x), -expf(alog4.y), -expf(alog4.z), -expf(alog4.w) };
    float dlt[4];
    #pragma unroll
    for (int k = 0; k < 4; ++k) dlt[k] = (d == n0 + k) ? 1.f : 0.f;

    float h[4] = { 0.f, 0.f, 0.f, 0.f };
    {
        const f32x4* sum = reinterpret_cast<const f32x4*>(ws + WS_SUM);
        for (int c2 = 0; c2 < c; ++c2) {
            const size_t sb = (((size_t)b * CH + c2) * DI + d) * DS + n0;
            #pragma unroll
            for (int k = 0; k < 4; ++k) {
                const f32x4 s = sum[sb + k];
                h[k] = fminf(fmaxf(fmaf(s.x, h[k], s.y), s.z), s.w);
            }
        }
    }
    __syncthreads();

    const int t0 = c * CL;
    #pragma unroll 4
    for (int j = 0; j < CL; ++j) {
        const float pv = pd_s[j][dl];
        const float uv = ud_s[j][dl];
        const f32x4 bv = *reinterpret_cast<const f32x4*>(&bm_s[j][n0]);
        const float bva[4] = { bv.x, bv.y, bv.z, bv.w };
        #pragma unroll
        for (int k = 0; k < 4; ++k) {
            const float av = fmaf(pv, an[k], dlt[k]);
            h[k] = clampM(fmaf(av, h[k], uv * bva[k]));
        }
        f32x4 hv = { h[0], h[1], h[2], h[3] };
        *reinterpret_cast<f32x4*>(
            out + 1024 + (((size_t)(b * S_ + t0 + j)) * DI + d) * DS + n0) = hv;
    }

    if (c == CH - 1) {
        const f32x4 cm = *reinterpret_cast<const f32x4*>(ws + WS_CML + b * DS + n0);
        float v = h[0] * cm.x + h[1] * cm.y + h[2] * cm.z + h[3] * cm.w;
        v += __shfl_xor(v, 1);
        v += __shfl_xor(v, 2);
        v += __shfl_xor(v, 4);
        v += __shfl_xor(v, 8);
        if ((tid & 15) == 0)
            out[b * DI + d] = v + Dp[d] * x[((size_t)(b * S_) + S_ - 1) * DI + d];
    }
}

extern "C" void kernel_launch(void* const* d_in, const int* in_sizes, int n_in,
                              void* d_out, int out_size, void* d_ws, size_t ws_size,
                              hipStream_t stream)
{
    const float* x     = (const float*)d_in[0];
    const float* Wx    = (const float*)d_in[1];
    const float* bx    = (const float*)d_in[2];
    const float* Wdt   = (const float*)d_in[3];
    const float* bdt   = (const float*)d_in[4];
    const float* A_log = (const float*)d_in[5];
    const float* Dp    = (const float*)d_in[6];
    float* out = (float*)d_out;
    float* ws  = (float*)d_ws;

    ssm_k1   <<<B_ * S_ / 8, 64, 0, stream>>>(x, Wx, bx, Wdt, bdt, A_log, ws);
    ssm_kA   <<<B_ * CH * 16, 256, 0, stream>>>(ws, A_log);
    ssm_wtest<<<B_ * CH * 4, 256, 0, stream>>>(out, 12);
    ssm_kC   <<<B_ * CH * 4, 256, 0, stream>>>(ws, x, A_log, Dp, out);
}

// Round 15
// 186.415 us; speedup vs baseline: 4.5373x; 1.5460x over previous
//
#include <hip/hip_runtime.h>
#include <cmath>

#define B_  16
#define S_  512
#define DI  64
#define DS  64
#define RR  4
#define CH  8
#define CL  64
#define CLIPM 1.0e6f

typedef float f32x4 __attribute__((ext_vector_type(4)));

// ws layout (floats):
#define WS_U    524288        // u     [B*S][DI]
#define WS_BM   1048576       // bm    [B*S][DS]
#define WS_CML  1572864       // cml   [B][DS]
#define WS_SUM  1573888       // f32x4 sums [B][CH][DI][DS]  (8 MB)

__device__ __forceinline__ float clampM(float v) {
    return fminf(fmaxf(v, -CLIPM), CLIPM);
}

__device__ __forceinline__ float opaque_zero() {
    float z = 0.f;
    asm volatile("" : "+v"(z));
    return z;
}

__device__ __forceinline__ float dot64(const float* __restrict__ row,
                                       const float* xsv) {
    float a = 0.f;
    #pragma unroll
    for (int i = 0; i < 16; ++i) {
        const f32x4 w  = *reinterpret_cast<const f32x4*>(row + 4 * i);
        const f32x4 xv = *reinterpret_cast<const f32x4*>(xsv + 4 * i);
        a += w.x * xv.x + w.y * xv.y + w.z * xv.z + w.w * xv.w;
    }
    return a;
}

__global__ void ssm_noop() {}

// k1: production (R12), unchanged.
__global__ __launch_bounds__(64)
void ssm_k1(const float* __restrict__ x, const float* __restrict__ Wx,
            const float* __restrict__ bx, const float* __restrict__ Wdt,
            const float* __restrict__ bdt, const float* __restrict__ A_log,
            float* __restrict__ ws)
{
    __shared__ float xs[8][DI];
    __shared__ float dtr_s[8][RR];
    const int bt0  = blockIdx.x * 8;
    const int lane = threadIdx.x;

    #pragma unroll
    for (int r = 0; r < 8; ++r)
        xs[r][lane] = x[(size_t)(bt0 + r) * DI + lane];
    const float a_l = -expf(A_log[lane]);
    const float bxl = bx[lane];
    __syncthreads();

    f32x4 wxr[16];
    {
        const float* wr = Wx + lane * DI;
        #pragma unroll
        for (int i = 0; i < 16; ++i)
            wxr[i] = *reinterpret_cast<const f32x4*>(wr + 4 * i);
    }

    float accB[8];
    #pragma unroll
    for (int r = 0; r < 8; ++r) {
        float a = bxl;
        #pragma unroll
        for (int i = 0; i < 16; ++i) {
            const f32x4 xv4 = *reinterpret_cast<const f32x4*>(&xs[r][4 * i]);
            a += wxr[i].x * xv4.x + wxr[i].y * xv4.y + wxr[i].z * xv4.z + wxr[i].w * xv4.w;
        }
        accB[r] = a;
    }

    if (lane < 32) {
        const int j = lane & 3, r = lane >> 2;
        dtr_s[r][j] = bx[DS + j] + dot64(Wx + (DS + j) * DI, &xs[r][0]);
    }
    __syncthreads();

    float qv = a_l * a_l;
    #pragma unroll
    for (int off = 32; off > 0; off >>= 1) qv += __shfl_xor(qv, off);

    const f32x4 wdt4 = *reinterpret_cast<const f32x4*>(Wdt + lane * RR);
    const float bdtl = bdt[lane];

    #pragma unroll
    for (int r = 0; r < 8; ++r) {
        float dtv = bdtl + dtr_s[r][0] * wdt4.x + dtr_s[r][1] * wdt4.y
                         + dtr_s[r][2] * wdt4.z + dtr_s[r][3] * wdt4.w;
        float sv = a_l * dtv;
        #pragma unroll
        for (int off = 32; off > 0; off >>= 1) sv += __shfl_xor(sv, off);

        const float E   = expm1f(sv);
        const float phi = (fabsf(sv) < 1e-3f)
                            ? fmaf(sv, fmaf(sv, 1.0f / 6.0f, 0.5f), 1.0f)
                            : (E / sv);
        const int bt = bt0 + r;
        ws[(size_t)bt * DI + lane]         = phi * dtv;
        ws[WS_U + (size_t)bt * DI + lane]  = xs[r][lane] * (E / qv) * a_l;
        ws[WS_BM + (size_t)bt * DI + lane] = accB[r];
    }

    if ((bt0 & (S_ - 1)) == S_ - 8) {
        ws[WS_CML + (bt0 >> 9) * DS + lane] =
            bx[DS + RR + lane] + dot64(Wx + (DS + RR + lane) * DI, &xs[7][0]);
    }
}

// kA: production (R12), unchanged.
__global__ __launch_bounds__(256)
void ssm_kA(float* __restrict__ ws, const float* __restrict__ A_log)
{
    __shared__ float pd_s[CL][4];
    __shared__ float ud_s[CL][4];
    __shared__ float bm_s[CL][DS];

    const int tid = threadIdx.x;
    const int dq  = blockIdx.x & 15;
    const int c   = (blockIdx.x >> 4) & 7;
    const int b   = blockIdx.x >> 7;
    const int d0  = dq * 4;

    const float* pg = ws + (size_t)(b * S_ + c * CL) * DI;
    const float* ug = ws + WS_U  + (size_t)(b * S_ + c * CL) * DI;
    const float* bg = ws + WS_BM + (size_t)(b * S_ + c * CL) * DI;

    if (tid < CL) {
        *reinterpret_cast<f32x4*>(&pd_s[tid][0]) =
            *reinterpret_cast<const f32x4*>(pg + (size_t)tid * DI + d0);
    } else if (tid < 2 * CL) {
        const int t = tid - CL;
        *reinterpret_cast<f32x4*>(&ud_s[t][0]) =
            *reinterpret_cast<const f32x4*>(ug + (size_t)t * DI + d0);
    }
    {
        const int col = (tid & 15) * 4;
        #pragma unroll
        for (int k = 0; k < 4; ++k) {
            const int t = (tid >> 4) + 16 * k;
            *reinterpret_cast<f32x4*>(&bm_s[t][col]) =
                *reinterpret_cast<const f32x4*>(bg + (size_t)t * DI + col);
        }
    }
    __syncthreads();

    const int w = tid >> 6;
    const int n = tid & 63;
    const int d = d0 + w;

    const float a_n   = -expf(A_log[n]);
    const float delta = (d == n) ? 1.0f : 0.0f;

    float al = 1.f, be = 0.f, lo = -CLIPM, hi = CLIPM;
    #pragma unroll 8
    for (int j = 0; j < CL; ++j) {
        const float pv = pd_s[j][w];
        const float uv = ud_s[j][w];
        const float bv = bm_s[j][n];
        const float av = fmaf(pv, a_n, delta);
        const float wk = uv * bv;
        al = al * av;
        be = fmaf(av, be, wk);
        const float u1 = fmaf(av, lo, wk);
        const float u2 = fmaf(av, hi, wk);
        lo = clampM(fminf(u1, u2));
        hi = clampM(fmaxf(u1, u2));
    }

    f32x4* sum = reinterpret_cast<f32x4*>(ws + WS_SUM);
    f32x4 s = { al, be, lo, hi };
    sum[(((size_t)b * CH + c) * DI + d) * DS + n] = s;
}

// kC: production structure (R12) + rep loop around replay+store ONLY.
// Each rep resets h to h0 (opaque zero keeps the recompute live); stored
// values identical every rep -> idempotent; y-epilogue uses final h.
__global__ __launch_bounds__(256)
void ssm_kC(const float* __restrict__ ws, const float* __restrict__ x,
            const float* __restrict__ A_log, const float* __restrict__ Dp,
            float* __restrict__ out, int reps)
{
    __shared__ float pd_s[CL][16];
    __shared__ float ud_s[CL][16];
    __shared__ float bm_s[CL][DS];

    const int tid = threadIdx.x;
    const int dg  = blockIdx.x & 3;
    const int c   = (blockIdx.x >> 2) & 7;
    const int b   = blockIdx.x >> 5;
    const int dl  = tid >> 4;
    const int n0  = (tid & 15) << 2;
    const int d0  = dg * 16;
    const int d   = d0 + dl;

    const float* pg = ws + (size_t)(b * S_ + c * CL) * DI;
    const float* ug = ws + WS_U  + (size_t)(b * S_ + c * CL) * DI;
    const float* bg = ws + WS_BM + (size_t)(b * S_ + c * CL) * DI;

    {
        const int t = tid >> 2, q = (tid & 3) * 4;
        *reinterpret_cast<f32x4*>(&pd_s[t][q]) =
            *reinterpret_cast<const f32x4*>(pg + (size_t)t * DI + d0 + q);
        *reinterpret_cast<f32x4*>(&ud_s[t][q]) =
            *reinterpret_cast<const f32x4*>(ug + (size_t)t * DI + d0 + q);
        const int col = (tid & 15) * 4;
        #pragma unroll
        for (int k = 0; k < 4; ++k) {
            const int tr = (tid >> 4) + 16 * k;
            *reinterpret_cast<f32x4*>(&bm_s[tr][col]) =
                *reinterpret_cast<const f32x4*>(bg + (size_t)tr * DI + col);
        }
    }

    const f32x4 alog4 = *reinterpret_cast<const f32x4*>(A_log + n0);
    const float an[4] = { -expf(alog4.x), -expf(alog4.y), -expf(alog4.z), -expf(alog4.w) };
    float dlt[4];
    #pragma unroll
    for (int k = 0; k < 4; ++k) dlt[k] = (d == n0 + k) ? 1.f : 0.f;

    float h0[4] = { 0.f, 0.f, 0.f, 0.f };
    {
        const f32x4* sum = reinterpret_cast<const f32x4*>(ws + WS_SUM);
        for (int c2 = 0; c2 < c; ++c2) {
            const size_t sb = (((size_t)b * CH + c2) * DI + d) * DS + n0;
            #pragma unroll
            for (int k = 0; k < 4; ++k) {
                const f32x4 s = sum[sb + k];
                h0[k] = fminf(fmaxf(fmaf(s.x, h0[k], s.y), s.z), s.w);
            }
        }
    }
    __syncthreads();

    float h[4];
    const int t0 = c * CL;
    for (int rep = 0; rep < reps; ++rep) {
        const float z = opaque_zero();
        #pragma unroll
        for (int k = 0; k < 4; ++k) h[k] = h0[k] + z;
        #pragma unroll 4
        for (int j = 0; j < CL; ++j) {
            const float pv = pd_s[j][dl];
            const float uv = ud_s[j][dl];
            const f32x4 bv = *reinterpret_cast<const f32x4*>(&bm_s[j][n0]);
            const float bva[4] = { bv.x, bv.y, bv.z, bv.w };
            #pragma unroll
            for (int k = 0; k < 4; ++k) {
                const float av = fmaf(pv, an[k], dlt[k]);
                h[k] = clampM(fmaf(av, h[k], uv * bva[k]));
            }
            f32x4 hv = { h[0], h[1], h[2], h[3] };
            *reinterpret_cast<f32x4*>(
                out + 1024 + (((size_t)(b * S_ + t0 + j)) * DI + d) * DS + n0) = hv;
        }
    }

    if (c == CH - 1) {
        const f32x4 cm = *reinterpret_cast<const f32x4*>(ws + WS_CML + b * DS + n0);
        float v = h[0] * cm.x + h[1] * cm.y + h[2] * cm.z + h[3] * cm.w;
        v += __shfl_xor(v, 1);
        v += __shfl_xor(v, 2);
        v += __shfl_xor(v, 4);
        v += __shfl_xor(v, 8);
        if ((tid & 15) == 0)
            out[b * DI + d] = v + Dp[d] * x[((size_t)(b * S_) + S_ - 1) * DI + d];
    }
}

extern "C" void kernel_launch(void* const* d_in, const int* in_sizes, int n_in,
                              void* d_out, int out_size, void* d_ws, size_t ws_size,
                              hipStream_t stream)
{
    const float* x     = (const float*)d_in[0];
    const float* Wx    = (const float*)d_in[1];
    const float* bx    = (const float*)d_in[2];
    const float* Wdt   = (const float*)d_in[3];
    const float* bdt   = (const float*)d_in[4];
    const float* A_log = (const float*)d_in[5];
    const float* Dp    = (const float*)d_in[6];
    float* out = (float*)d_out;
    float* ws  = (float*)d_ws;

    ssm_k1<<<B_ * S_ / 8, 64, 0, stream>>>(x, Wx, bx, Wdt, bdt, A_log, ws);
    ssm_noop<<<1, 64, 0, stream>>>();
    ssm_noop<<<1, 64, 0, stream>>>();
    ssm_noop<<<1, 64, 0, stream>>>();
    ssm_kA<<<B_ * CH * 16, 256, 0, stream>>>(ws, A_log);
    ssm_noop<<<1, 64, 0, stream>>>();
    ssm_noop<<<1, 64, 0, stream>>>();
    ssm_noop<<<1, 64, 0, stream>>>();
    ssm_kC<<<B_ * CH * 4, 256, 0, stream>>>(ws, x, A_log, Dp, out, 7);
}